// Round 6
// baseline (176.817 us; speedup 1.0000x reference)
//
#include <hip/hip_runtime.h>
#include <hip/hip_bf16.h>

// Problem constants
#define BB 8
#define SS 2048
#define DD 1024
#define OO 1024
#define MM (BB * SS)   // 16384
#define KK DD          // 1024
#define NN OO          // 1024
#define CC 64          // chunks
#define LL 32          // chunk length (CC*LL == SS)

typedef __bf16 bf16x8 __attribute__((ext_vector_type(8)));
typedef __bf16 bf16x4 __attribute__((ext_vector_type(4)));
typedef float floatx4 __attribute__((ext_vector_type(4)));

__device__ __forceinline__ float4 fma4(float4 h, float4 a, float4 v) {
    h.x = fmaf(h.x, a.x, v.x);
    h.y = fmaf(h.y, a.y, v.y);
    h.z = fmaf(h.z, a.z, v.z);
    h.w = fmaf(h.w, a.w, v.w);
    return h;
}

// ---------------- Kernel 1: fused per-chunk carries + BC transpose/cast ----------------
__global__ __launch_bounds__(256) void prep(const float* __restrict__ x,
                                            const float* __restrict__ A,
                                            float* __restrict__ carry,
                                            const float* __restrict__ BC,
                                            __bf16* __restrict__ BCt) {
    __shared__ float tile[32][33];
    const int id = blockIdx.x;
    if (id < BB * CC) {
        const int c = id & (CC - 1);
        const int b = id >> 6;          // id / CC
        const int i4 = threadIdx.x;     // float4 index over D (0..255)
        const float4 a = ((const float4*)A)[i4];
        const float4* xp = (const float4*)(x + ((size_t)b * SS + (size_t)c * LL) * DD) + i4;
        float4 h = make_float4(0.f, 0.f, 0.f, 0.f);
#pragma unroll
        for (int t0 = 0; t0 < LL; t0 += 8) {
            float4 v[8];
#pragma unroll
            for (int u = 0; u < 8; ++u) v[u] = xp[(size_t)(t0 + u) * (DD / 4)];
#pragma unroll
            for (int u = 0; u < 8; ++u) h = fma4(h, a, v[u]);
        }
        ((float4*)carry)[((size_t)b * CC + c) * (DD / 4) + i4] = h;
    } else {
        const int t = id - BB * CC;
        const int o0 = (t & 31) * 32;
        const int d0 = (t >> 5) * 32;
        const int tx = threadIdx.x & 31;
        const int ty = threadIdx.x >> 5;   // 0..7
#pragma unroll
        for (int i = 0; i < 4; ++i) {
            const int dd = ty + i * 8;
            tile[dd][tx] = BC[(size_t)(d0 + dd) * OO + o0 + tx];
        }
        __syncthreads();
#pragma unroll
        for (int i = 0; i < 4; ++i) {
            const int oo = ty + i * 8;
            BCt[(size_t)(o0 + oo) * DD + d0 + tx] = (__bf16)tile[tx][oo];
        }
    }
}

// ---------------- Kernel 2: emit hs (bf16), chunk prefix computed in-kernel ----------------
__global__ __launch_bounds__(256) void scan_emit(const float* __restrict__ x,
                                                 const float* __restrict__ A,
                                                 const float* __restrict__ carry,
                                                 __bf16* __restrict__ hs) {
    const int id = blockIdx.x;
    const int c = id & (CC - 1);
    const int b = id >> 6;
    const int i4 = threadIdx.x;
    const float4 a = ((const float4*)A)[i4];
    float4 aL = a;
#pragma unroll
    for (int i = 0; i < 5; ++i) { aL.x *= aL.x; aL.y *= aL.y; aL.z *= aL.z; aL.w *= aL.w; }
    float4 h = make_float4(0.f, 0.f, 0.f, 0.f);
    const float4* cp = (const float4*)carry + (size_t)b * CC * (DD / 4) + i4;
    for (int j = 0; j < c; ++j) {
        const float4 cv = cp[(size_t)j * (DD / 4)];
        h.x = fmaf(h.x, aL.x, cv.x);
        h.y = fmaf(h.y, aL.y, cv.y);
        h.z = fmaf(h.z, aL.z, cv.z);
        h.w = fmaf(h.w, aL.w, cv.w);
    }
    const size_t base = ((size_t)b * SS + (size_t)c * LL) * DD;
    const float4* xp = (const float4*)(x + base) + i4;
    bf16x4* hp = (bf16x4*)(hs + base) + i4;
#pragma unroll
    for (int t0 = 0; t0 < LL; t0 += 8) {
        float4 v[8];
#pragma unroll
        for (int u = 0; u < 8; ++u) v[u] = xp[(size_t)(t0 + u) * (DD / 4)];
#pragma unroll
        for (int u = 0; u < 8; ++u) {
            h = fma4(h, a, v[u]);
            bf16x4 o;
            o[0] = (__bf16)h.x; o[1] = (__bf16)h.y; o[2] = (__bf16)h.z; o[3] = (__bf16)h.w;
            hp[(size_t)(t0 + u) * (DD / 4)] = o;
        }
    }
}

// ---------------- GEMM: C[m,n] = sum_k A[m,k] * Bt[n,k] ----------------
// 256x256 block tile (512 thr, 8 waves of 64x128), dbuf TK=32, one barrier/iter,
// XOR bank swizzle. Rationale: the global_load_lds staging path is the binding
// resource (~16 B/cyc/CU measured across R4/R5/m97); 256^2 tiles halve total
// staged bytes (537 MB -> 268 MB) vs 128^2.
#define TM 256
#define TN 256
#define TK 32
#define NITER (KK / TK)

__device__ __forceinline__ void async16(void* lds, const void* g) {
    __builtin_amdgcn_global_load_lds(
        (__attribute__((address_space(1))) void*)(void*)g,
        (__attribute__((address_space(3))) void*)lds, 16, 0, 0);
}

__global__ __launch_bounds__(512, 2) void gemm_bt(const __bf16* __restrict__ Am,
                                                  const __bf16* __restrict__ Bt,
                                                  float* __restrict__ C) {
    __shared__ __align__(16) __bf16 As[2][TM * TK];
    __shared__ __align__(16) __bf16 Bs[2][TN * TK];

    const int tid = threadIdx.x;
    const int wave = tid >> 6;
    const int lane = tid & 63;
    const int wm = (wave >> 1) * 64;    // {0,64,128,192}
    const int wn = (wave & 1) * 128;    // {0,128}
    const int lanelo = lane & 15;
    const int quad = lane >> 4;
    const int tile_m = blockIdx.x * TM;   // m varies fastest across block ids
    const int tile_n = blockIdx.y * TN;

    // staging: LDS slot cid holds global chunk (r, q) with q XOR-swizzled
    const int cid0 = tid;
    const int cid1 = tid + 512;
    const int r0 = cid0 >> 2, q0 = ((cid0 & 3) ^ ((r0 >> 1) & 3)) * 8;
    const int r1 = cid1 >> 2, q1 = ((cid1 & 3) ^ ((r1 >> 1) & 3)) * 8;

    const __bf16* Ab  = Am + (size_t)(tile_m + r0) * KK + q0;
    const __bf16* Ab1 = Am + (size_t)(tile_m + r1) * KK + q1;
    const __bf16* Bb  = Bt + (size_t)(tile_n + r0) * KK + q0;
    const __bf16* Bb1 = Bt + (size_t)(tile_n + r1) * KK + q1;

    // read-side swizzled k-group offset (elements)
    const int fs = (lanelo >> 1) & 3;
    const int kq = (quad ^ fs) * 8;

    floatx4 acc[4][8];
#pragma unroll
    for (int i = 0; i < 4; ++i)
#pragma unroll
        for (int j = 0; j < 8; ++j) acc[i][j] = (floatx4){0.f, 0.f, 0.f, 0.f};

    // prologue: stage tile 0 into buffer 0
    async16(&As[0][cid0 * 8], Ab);
    async16(&As[0][cid1 * 8], Ab1);
    async16(&Bs[0][cid0 * 8], Bb);
    async16(&Bs[0][cid1 * 8], Bb1);

    int cur = 0;
    for (int i = 0; i < NITER; ++i) {
        __syncthreads();   // buf[cur] staged; prior readers of buf[cur^1] done
        if (i + 1 < NITER) {
            const int k = (i + 1) * TK;
            async16(&As[cur ^ 1][cid0 * 8], Ab + k);
            async16(&As[cur ^ 1][cid1 * 8], Ab1 + k);
            async16(&Bs[cur ^ 1][cid0 * 8], Bb + k);
            async16(&Bs[cur ^ 1][cid1 * 8], Bb1 + k);
        }

        bf16x8 af[4], bf[8];
#pragma unroll
        for (int ii = 0; ii < 4; ++ii)
            af[ii] = *(const bf16x8*)(&As[cur][(wm + ii * 16 + lanelo) * TK + kq]);
#pragma unroll
        for (int j = 0; j < 8; ++j)
            bf[j] = *(const bf16x8*)(&Bs[cur][(wn + j * 16 + lanelo) * TK + kq]);

#pragma unroll
        for (int ii = 0; ii < 4; ++ii)
#pragma unroll
            for (int j = 0; j < 8; ++j)
                acc[ii][j] = __builtin_amdgcn_mfma_f32_16x16x32_bf16(af[ii], bf[j], acc[ii][j], 0, 0, 0);
        cur ^= 1;
    }

    // epilogue: row = quad*4 + reg, col = lanelo
#pragma unroll
    for (int i = 0; i < 4; ++i) {
        const int row = tile_m + wm + i * 16 + quad * 4;
#pragma unroll
        for (int r = 0; r < 4; ++r) {
            float* crow = C + (size_t)(row + r) * NN + tile_n + wn + lanelo;
#pragma unroll
            for (int j = 0; j < 8; ++j) crow[j * 16] = acc[i][j][r];
        }
    }
}

extern "C" void kernel_launch(void* const* d_in, const int* in_sizes, int n_in,
                              void* d_out, int out_size, void* d_ws, size_t ws_size,
                              hipStream_t stream) {
    const float* x  = (const float*)d_in[0];   // [B,S,D]
    const float* A  = (const float*)d_in[1];   // [D]
    const float* BC = (const float*)d_in[2];   // [D,O]
    float* out = (float*)d_out;                // [B,S,O]

    char* ws = (char*)d_ws;
    __bf16* hs   = (__bf16*)ws;                                  // 33,554,432 B
    float* carry = (float*)(ws + 33554432);                      // 2 MB (BB*CC*DD*4)
    __bf16* BCt  = (__bf16*)(ws + 33554432 + 2097152);           // 2 MB

    prep<<<dim3(BB * CC + 1024), 256, 0, stream>>>(x, A, carry, BC, BCt);
    scan_emit<<<dim3(BB * CC), 256, 0, stream>>>(x, A, carry, hs);
    gemm_bt<<<dim3(MM / TM, NN / TN), 512, 0, stream>>>(hs, BCt, out);
}